// Round 5
// baseline (146.057 us; speedup 1.0000x reference)
//
#include <hip/hip_runtime.h>

// Flash-attention forward, causal, B=4 H=16 S=2048 D=128, fp32 in/out.
// Round 5: cross-tile software pipeline on the 8-wave 32x32 structure.
//   - phase t: QK^T(t) MFMA burst interleaved (same basic block) with
//     mask+softmax+cvt+PV of tile t-1  -> LDS/MFMA pipes stay fed
//   - 3 LDS buffers (96KB): stage(t+1) / QK(t) / PV(t-1) never collide,
//     single barrier per tile
//   - fused prepass (K->bf16 convert + V->V^T bf16 transpose in one kernel)
//   - float4 epilogue stores

#define SLEN 2048
#define DDIM 128
#define NBH  64
#define QB   256
#define KB   64

typedef __bf16 bf16x8 __attribute__((ext_vector_type(8)));
typedef float  f32x16 __attribute__((ext_vector_type(16)));
typedef float  f32x4  __attribute__((ext_vector_type(4)));
typedef unsigned uint32x4 __attribute__((ext_vector_type(4)));
typedef unsigned short ushort_t;
typedef ushort_t ushort8 __attribute__((ext_vector_type(8)));

__device__ inline ushort_t f2bf(float f) {
  union { float f; unsigned u; } v; v.f = f;
  unsigned u = v.u;
  u += 0x7FFFu + ((u >> 16) & 1u);   // RNE, finite inputs only
  return (ushort_t)(u >> 16);
}

__device__ inline unsigned cvtpk_bf16(float lo, float hi) {
  unsigned r;
  asm("v_cvt_pk_bf16_f32 %0, %1, %2" : "=v"(r) : "v"(lo), "v"(hi));
  return r;
}

__device__ inline float exp2_fast(float x) {
  float r;
  asm("v_exp_f32 %0, %1" : "=v"(r) : "v"(x));
  return r;
}

// ------------- fused pre-pass: K->bf16 convert + V->V^T bf16 -------------
__global__ __launch_bounds__(256) void prepass_kernel(
    const float* __restrict__ K, const float* __restrict__ V,
    ushort_t* __restrict__ Kb, ushort_t* __restrict__ Vt) {
  __shared__ float t[64][33];
  if (blockIdx.x < 2048) {            // ---- K convert ----
    const int n4 = (int)((size_t)NBH * SLEN * DDIM / 4);
    const int stride = 2048 * 256;
    for (int i = blockIdx.x * 256 + threadIdx.x; i < n4; i += stride) {
      float4 x = reinterpret_cast<const float4*>(K)[i];
      unsigned lo = (unsigned)f2bf(x.x) | ((unsigned)f2bf(x.y) << 16);
      unsigned hi = (unsigned)f2bf(x.z) | ((unsigned)f2bf(x.w) << 16);
      reinterpret_cast<uint2*>(Kb)[i] = make_uint2(lo, hi);
    }
  } else {                            // ---- V transpose ----
    const int vb = (int)blockIdx.x - 2048;     // 8192 blocks
    const int bh = vb >> 7;
    const int d0 = ((vb >> 5) & 3) * 32;
    const int s0 = (vb & 31) * 64;
    const int tx = threadIdx.x & 31;
    const int ty = threadIdx.x >> 5;
    const float* src = V + ((size_t)bh * SLEN + s0) * DDIM + d0;
#pragma unroll
    for (int j = 0; j < 8; ++j) {
      int sl = ty + j * 8;
      t[sl][tx] = src[(size_t)sl * DDIM + tx];
    }
    __syncthreads();
    ushort_t* dst = Vt + ((size_t)bh * DDIM + d0) * SLEN + s0;
#pragma unroll
    for (int j = 0; j < 4; ++j) {
      int dl = ty + j * 8;
      unsigned lo = f2bf(t[tx * 2][dl]);
      unsigned hi = f2bf(t[tx * 2 + 1][dl]);
      *reinterpret_cast<unsigned*>(&dst[(size_t)dl * SLEN + tx * 2]) =
          lo | (hi << 16);
    }
  }
}

// ---- QK^T for tile TT into S[2] (no setprio: let softmax interleave) ----
#define QKT(S, TT) do {                                                      \
    const int _b = (TT) % 3;                                                 \
    _Pragma("unroll")                                                        \
    for (int mt = 0; mt < 2; ++mt) {                                         \
      f32x16 a;                                                              \
      _Pragma("unroll")                                                      \
      for (int r = 0; r < 16; ++r) a[r] = 0.f;                               \
      int row = mt * 32 + l31;                                               \
      int sw = row & 7;                                                      \
      _Pragma("unroll")                                                      \
      for (int ds = 0; ds < 8; ++ds) {                                       \
        int c = ds * 2 + hi;                                                 \
        bf16x8 kf = *reinterpret_cast<const bf16x8*>(                        \
            &K_sh[_b][row * DDIM + ((c ^ sw) << 3)]);                        \
        a = __builtin_amdgcn_mfma_f32_32x32x16_bf16(kf, qf[ds], a, 0, 0, 0); \
      }                                                                      \
      S[mt] = a;                                                             \
    }                                                                        \
  } while (0)

// ---- mask + online softmax + cvt/permlane + PV for tile U on S[2] ----
#define FINISH(S, U) do {                                                    \
    const int _u = (U);                                                      \
    const int _vb = _u % 3;                                                  \
    if (_u * 64 + 63 > q0w) {                                                \
      _Pragma("unroll")                                                      \
      for (int mt = 0; mt < 2; ++mt) {                                       \
        int kbase = _u * 64 + mt * 32 + 4 * hi;                              \
        _Pragma("unroll")                                                    \
        for (int r = 0; r < 16; ++r) {                                       \
          int krow = (r & 3) + 8 * (r >> 2);                                 \
          if (kbase + krow > qg) S[mt][r] = -3.0e38f;                        \
        }                                                                    \
      }                                                                      \
    }                                                                        \
    float p0 = S[0][0], p1 = S[0][1], p2 = S[0][2], p3 = S[0][3];            \
    _Pragma("unroll")                                                        \
    for (int r = 4; r < 16; r += 4) {                                        \
      p0 = fmaxf(p0, S[0][r]);     p1 = fmaxf(p1, S[0][r + 1]);              \
      p2 = fmaxf(p2, S[0][r + 2]); p3 = fmaxf(p3, S[0][r + 3]);              \
    }                                                                        \
    _Pragma("unroll")                                                        \
    for (int r = 0; r < 16; r += 4) {                                        \
      p0 = fmaxf(p0, S[1][r]);     p1 = fmaxf(p1, S[1][r + 1]);              \
      p2 = fmaxf(p2, S[1][r + 2]); p3 = fmaxf(p3, S[1][r + 3]);              \
    }                                                                        \
    float tm = fmaxf(fmaxf(p0, p1), fmaxf(p2, p3));                          \
    tm = fmaxf(tm, __shfl_xor(tm, 32));                                      \
    if (!__all(tm - m_run <= THR)) {                                         \
      float mnew  = fmaxf(m_run, tm);                                        \
      float alpha = exp2_fast(m_run - mnew);                                 \
      m_run = mnew; l_run *= alpha;                                          \
      _Pragma("unroll")                                                      \
      for (int dt = 0; dt < 4; ++dt)                                         \
        _Pragma("unroll")                                                    \
        for (int r = 0; r < 16; ++r) Oacc[dt][r] *= alpha;                   \
    }                                                                        \
    float s0 = 0.f, s1 = 0.f, s2 = 0.f, s3 = 0.f;                            \
    _Pragma("unroll")                                                        \
    for (int mt = 0; mt < 2; ++mt)                                           \
      _Pragma("unroll")                                                      \
      for (int r = 0; r < 16; r += 4) {                                      \
        float e0 = exp2_fast(S[mt][r + 0] - m_run);                          \
        float e1 = exp2_fast(S[mt][r + 1] - m_run);                          \
        float e2 = exp2_fast(S[mt][r + 2] - m_run);                          \
        float e3 = exp2_fast(S[mt][r + 3] - m_run);                          \
        S[mt][r + 0] = e0; S[mt][r + 1] = e1;                                \
        S[mt][r + 2] = e2; S[mt][r + 3] = e3;                                \
        s0 += e0; s1 += e1; s2 += e2; s3 += e3;                              \
      }                                                                      \
    float rs = (s0 + s1) + (s2 + s3);                                        \
    rs += __shfl_xor(rs, 32);                                                \
    l_run += rs;                                                             \
    uint32x4 pw[4];                                                          \
    _Pragma("unroll")                                                        \
    for (int ks = 0; ks < 4; ++ks) {                                         \
      const int mt = ks >> 1;                                                \
      const int hb = 8 * (ks & 1);                                           \
      unsigned X  = cvtpk_bf16(S[mt][hb + 0], S[mt][hb + 1]);                \
      unsigned X2 = cvtpk_bf16(S[mt][hb + 2], S[mt][hb + 3]);                \
      unsigned Y  = cvtpk_bf16(S[mt][hb + 4], S[mt][hb + 5]);                \
      unsigned Y2 = cvtpk_bf16(S[mt][hb + 6], S[mt][hb + 7]);                \
      asm("v_permlane32_swap_b32 %0, %1" : "+v"(X),  "+v"(Y));               \
      asm("v_permlane32_swap_b32 %0, %1" : "+v"(X2), "+v"(Y2));              \
      uint32x4 f; f.x = X; f.y = X2; f.z = Y; f.w = Y2;                      \
      pw[ks] = f;                                                            \
    }                                                                        \
    _Pragma("unroll")                                                        \
    for (int dt = 0; dt < 4; ++dt) {                                         \
      int row = dt * 32 + l31;                                               \
      int sw = row & 7;                                                      \
      __builtin_amdgcn_s_setprio(1);                                         \
      _Pragma("unroll")                                                      \
      for (int ks = 0; ks < 4; ++ks) {                                       \
        int c = ks * 2 + hi;                                                 \
        bf16x8 vf = *reinterpret_cast<const bf16x8*>(                        \
            &V_sh[_vb][row * 64 + ((c ^ sw) << 3)]);                         \
        Oacc[dt] = __builtin_amdgcn_mfma_f32_32x32x16_bf16(                  \
            vf, __builtin_bit_cast(bf16x8, pw[ks]), Oacc[dt], 0, 0, 0);      \
      }                                                                      \
      __builtin_amdgcn_s_setprio(0);                                         \
    }                                                                        \
  } while (0)

// ---------------- main kernel: 8 waves, 32x32 MFMA, pipelined ----------------
__global__ __launch_bounds__(512, 2) void fattn5_kernel(
    const float* __restrict__ Q, const ushort_t* __restrict__ Kb,
    const ushort_t* __restrict__ Vt, float* __restrict__ Out) {
  __shared__ ushort_t K_sh[3][KB * DDIM];   // 3 x 16KB
  __shared__ ushort_t V_sh[3][DDIM * KB];   // 3 x 16KB

  const int tid  = threadIdx.x;
  const int lane = tid & 63;
  const int wv   = tid >> 6;         // 0..7
  const int l31  = lane & 31;
  const int hi   = lane >> 5;        // 0/1
  const int qblk = (blockIdx.y >= 32) ? blockIdx.x : (7 - (int)blockIdx.x);
  const int bh   = blockIdx.y;

  // 1/sqrt(128) * log2(e): softmax runs in exp2 domain
  const float qscale = 0.12751744f;
  const float THR = 11.0f;           // defer-max threshold (log2 units)

  const float*    Qp = Q  + (size_t)bh * SLEN * DDIM;
  const ushort_t* Kp = Kb + (size_t)bh * SLEN * DDIM;
  const ushort_t* Vp = Vt + (size_t)bh * DDIM * SLEN;
  float*          Op = Out + (size_t)bh * SLEN * DDIM;

  const int q0w = qblk * QB + wv * 32;   // wave's first q row
  const int qg  = q0w + l31;             // this lane's q row

  // ---- Q fragments: B-operand of S^T = K·Q^T ----
  bf16x8 qf[8];
  {
    const float* qr = Qp + (size_t)qg * DDIM;
#pragma unroll
    for (int ds = 0; ds < 8; ++ds) {
      int d0 = ds * 16 + hi * 8;
      float4 x = *reinterpret_cast<const float4*>(qr + d0);
      float4 y = *reinterpret_cast<const float4*>(qr + d0 + 4);
      ushort8 uu;
      uu[0] = f2bf(x.x * qscale); uu[1] = f2bf(x.y * qscale);
      uu[2] = f2bf(x.z * qscale); uu[3] = f2bf(x.w * qscale);
      uu[4] = f2bf(y.x * qscale); uu[5] = f2bf(y.y * qscale);
      uu[6] = f2bf(y.z * qscale); uu[7] = f2bf(y.w * qscale);
      qf[ds] = __builtin_bit_cast(bf16x8, uu);
    }
  }

  f32x16 Oacc[4];
#pragma unroll
  for (int dt = 0; dt < 4; ++dt)
#pragma unroll
    for (int r = 0; r < 16; ++r) Oacc[dt][r] = 0.f;
  float m_run = -3.0e38f, l_run = 0.f;

  const int last_kb = qblk * 4 + 3;          // WG-uniform; ntiles = 4qblk+4
  const int lkw     = 4 * qblk + (wv >> 1);  // wave's last needed tile

  auto stage = [&](int buf, int kb) {
    const ushort_t* ksrc = Kp + (size_t)kb * KB * DDIM;
#pragma unroll
    for (int j = 0; j < 2; ++j) {
      int chunk = wv * 128 + j * 64 + lane;
      int row = chunk >> 4, c = chunk & 15;
      const ushort_t* g = ksrc + row * DDIM + ((c ^ (row & 7)) << 3);
      ushort_t* l = &K_sh[buf][(wv * 128 + j * 64) * 8];
      __builtin_amdgcn_global_load_lds(
          (const __attribute__((address_space(1))) unsigned*)g,
          (__attribute__((address_space(3))) unsigned*)l, 16, 0, 0);
    }
    const ushort_t* vsrc = Vp + (size_t)kb * KB;
#pragma unroll
    for (int j = 0; j < 2; ++j) {
      int chunk = wv * 128 + j * 64 + lane;
      int row = chunk >> 3, c = chunk & 7;
      const ushort_t* g = vsrc + (size_t)row * SLEN + ((c ^ (row & 7)) << 3);
      ushort_t* l = &V_sh[buf][(wv * 128 + j * 64) * 8];
      __builtin_amdgcn_global_load_lds(
          (const __attribute__((address_space(1))) unsigned*)g,
          (__attribute__((address_space(3))) unsigned*)l, 16, 0, 0);
    }
  };

  f32x16 sacA[2], sacB[2];

  stage(0, 0);

  // ---- peel t = 0 ----
  __syncthreads();
  stage(1, 1);
  QKT(sacA, 0);

  // ---- peel t = 1 ----
  __syncthreads();
  if (1 < last_kb) stage(2, 2);
  if (1 <= lkw)           { QKT(sacB, 1); FINISH(sacA, 0); }
  else if (lkw == 0)      { FINISH(sacA, 0); }

  // ---- main pipeline, 2 tiles per iteration ----
  for (int t = 2; t <= last_kb; t += 2) {
    __syncthreads();
    if (t < last_kb) stage((t + 1) % 3, t + 1);
    if (t <= lkw)            { QKT(sacA, t); FINISH(sacB, t - 1); }
    else if (t == lkw + 1)   { FINISH(sacB, t - 1); }

    __syncthreads();
    if (t + 1 < last_kb) stage((t + 2) % 3, t + 2);
    if (t + 1 <= lkw)          { QKT(sacB, t + 1); FINISH(sacA, t); }
    else if (t + 1 == lkw + 1) { FINISH(sacA, t); }
  }

  // ---- drain: tile last_kb (odd -> sacB) for waves that needed it ----
  if (lkw == last_kb) { FINISH(sacB, last_kb); }

  // ---- epilogue: O[q][d] = O^T normalized, float4 stores ----
  {
    float invl = 1.0f / l_run;
    float* orow = Op + (size_t)qg * DDIM;
#pragma unroll
    for (int dt = 0; dt < 4; ++dt)
#pragma unroll
      for (int rq = 0; rq < 4; ++rq) {
        float4 o;
        o.x = Oacc[dt][rq * 4 + 0] * invl;
        o.y = Oacc[dt][rq * 4 + 1] * invl;
        o.z = Oacc[dt][rq * 4 + 2] * invl;
        o.w = Oacc[dt][rq * 4 + 3] * invl;
        int d = dt * 32 + 8 * rq + 4 * hi;
        *reinterpret_cast<float4*>(orow + d) = o;
      }
  }
}

// ---------------- fallback (fp32-direct kernel, used if ws too small) --------
__global__ __launch_bounds__(256) void fattn_kernel(
    const float* __restrict__ Q, const float* __restrict__ K,
    const float* __restrict__ V, float* __restrict__ Out) {
  __shared__ ushort_t Kf_sh[64 * 128];
  __shared__ ushort_t Vf_sh[128 * 64];
  __shared__ ushort_t P_sh[4][16 * 64];

  const int tid  = threadIdx.x;
  const int lane = tid & 63;
  const int wv   = tid >> 6;
  const int l16  = lane & 15;
  const int lhi  = lane >> 4;
  const int qblk = blockIdx.x;
  const int bh   = blockIdx.y;
  const float scale = 0.08838834764831845f;

  const size_t base = (size_t)bh * SLEN * DDIM;
  const float* Qp = Q + base;
  const float* Kp = K + base;
  const float* Vp = V + base;
  float*       Op = Out + base;

  bf16x8 qf[4];
  {
    const int qrow = qblk * 64 + wv * 16 + l16;
    const float* qr = Qp + (size_t)qrow * DDIM;
#pragma unroll
    for (int dc = 0; dc < 4; ++dc) {
      int d0 = dc * 32 + lhi * 8;
      float4 x = *reinterpret_cast<const float4*>(qr + d0);
      float4 y = *reinterpret_cast<const float4*>(qr + d0 + 4);
      ushort8 uu;
      uu[0] = f2bf(x.x * scale); uu[1] = f2bf(x.y * scale);
      uu[2] = f2bf(x.z * scale); uu[3] = f2bf(x.w * scale);
      uu[4] = f2bf(y.x * scale); uu[5] = f2bf(y.y * scale);
      uu[6] = f2bf(y.z * scale); uu[7] = f2bf(y.w * scale);
      qf[dc] = __builtin_bit_cast(bf16x8, uu);
    }
  }

  f32x4 Oacc[8];
#pragma unroll
  for (int i = 0; i < 8; ++i) Oacc[i] = (f32x4){0.f, 0.f, 0.f, 0.f};
  float m_run[4], l_run[4];
#pragma unroll
  for (int r = 0; r < 4; ++r) { m_run[r] = -3.0e38f; l_run[r] = 0.f; }

  for (int kb = 0; kb <= qblk; ++kb) {
    __syncthreads();
    {
      const float* src = Kp + (size_t)kb * 64 * DDIM;
#pragma unroll
      for (int it = 0; it < 8; ++it) {
        int idx4 = it * 256 + tid;
        int r  = idx4 >> 5;
        int c4 = idx4 & 31;
        float4 x = *reinterpret_cast<const float4*>(src + r * DDIM + c4 * 4);
        unsigned lo = ((unsigned)f2bf(x.y) << 16) | f2bf(x.x);
        unsigned hh = ((unsigned)f2bf(x.w) << 16) | f2bf(x.z);
        int e = (r * 128 + c4 * 4) ^ ((r & 7) << 3);
        *reinterpret_cast<uint2*>(&Kf_sh[e]) = make_uint2(lo, hh);
      }
      const float* vs = Vp + (size_t)kb * 64 * DDIM;
#pragma unroll
      for (int it = 0; it < 8; ++it) {
        int idx4 = it * 256 + tid;
        int r  = idx4 >> 5;
        int c4 = idx4 & 31;
        float4 x = *reinterpret_cast<const float4*>(vs + r * DDIM + c4 * 4);
        int c0 = c4 * 4;
        float vals[4] = {x.x, x.y, x.z, x.w};
#pragma unroll
        for (int j = 0; j < 4; ++j) {
          int d = c0 + j;
          Vf_sh[(d * 64 + r) ^ ((d & 7) << 3)] = f2bf(vals[j]);
        }
      }
    }
    __syncthreads();

    f32x4 sacc[4];
#pragma unroll
    for (int g = 0; g < 4; ++g) {
      f32x4 acc = (f32x4){0.f, 0.f, 0.f, 0.f};
#pragma unroll
      for (int dc = 0; dc < 4; ++dc) {
        int row = g * 16 + l16;
        int e = (row * 128 + dc * 32 + lhi * 8) ^ ((row & 7) << 3);
        bf16x8 kf = *reinterpret_cast<const bf16x8*>(&Kf_sh[e]);
        acc = __builtin_amdgcn_mfma_f32_16x16x32_bf16(qf[dc], kf, acc, 0, 0, 0);
      }
      sacc[g] = acc;
    }

    if (kb == qblk) {
      int q0 = lhi * 4;
#pragma unroll
      for (int g = 0; g < 4; ++g) {
        int kcol = g * 16 + l16;
#pragma unroll
        for (int r = 0; r < 4; ++r) {
          if (kcol > wv * 16 + q0 + r) sacc[g][r] = -3.0e38f;
        }
      }
    }

    float tmax[4];
#pragma unroll
    for (int r = 0; r < 4; ++r)
      tmax[r] = fmaxf(fmaxf(sacc[0][r], sacc[1][r]),
                      fmaxf(sacc[2][r], sacc[3][r]));
#pragma unroll
    for (int x = 1; x < 16; x <<= 1) {
#pragma unroll
      for (int r = 0; r < 4; ++r)
        tmax[r] = fmaxf(tmax[r], __shfl_xor(tmax[r], x));
    }

    float alpha[4], mnew[4];
#pragma unroll
    for (int r = 0; r < 4; ++r) {
      mnew[r]  = fmaxf(m_run[r], tmax[r]);
      alpha[r] = __expf(m_run[r] - mnew[r]);
      m_run[r] = mnew[r];
    }

    float rsum[4] = {0.f, 0.f, 0.f, 0.f};
#pragma unroll
    for (int g = 0; g < 4; ++g) {
#pragma unroll
      for (int r = 0; r < 4; ++r) {
        float p = __expf(sacc[g][r] - mnew[r]);
        rsum[r] += p;
        int prow = lhi * 4 + r;
        P_sh[wv][(prow * 64 + g * 16 + l16) ^ ((prow & 7) << 3)] = f2bf(p);
      }
    }
#pragma unroll
    for (int x = 1; x < 16; x <<= 1) {
#pragma unroll
      for (int r = 0; r < 4; ++r) rsum[r] += __shfl_xor(rsum[r], x);
    }
#pragma unroll
    for (int r = 0; r < 4; ++r) l_run[r] = l_run[r] * alpha[r] + rsum[r];

#pragma unroll
    for (int dg = 0; dg < 8; ++dg)
#pragma unroll
      for (int r = 0; r < 4; ++r) Oacc[dg][r] *= alpha[r];

    bf16x8 pf[2];
#pragma unroll
    for (int kc = 0; kc < 2; ++kc) {
      int e = (l16 * 64 + kc * 32 + lhi * 8) ^ ((l16 & 7) << 3);
      pf[kc] = *reinterpret_cast<const bf16x8*>(&P_sh[wv][e]);
    }
#pragma unroll
    for (int dg = 0; dg < 8; ++dg) {
#pragma unroll
      for (int kc = 0; kc < 2; ++kc) {
        int row = dg * 16 + l16;
        int e = (row * 64 + kc * 32 + lhi * 8) ^ ((row & 7) << 3);
        bf16x8 vf = *reinterpret_cast<const bf16x8*>(&Vf_sh[e]);
        Oacc[dg] = __builtin_amdgcn_mfma_f32_16x16x32_bf16(pf[kc], vf, Oacc[dg], 0, 0, 0);
      }
    }
  }

#pragma unroll
  for (int r = 0; r < 4; ++r) {
    float inv = 1.0f / l_run[r];
    int q = qblk * 64 + wv * 16 + lhi * 4 + r;
    float* orow = Op + (size_t)q * DDIM;
#pragma unroll
    for (int dg = 0; dg < 8; ++dg)
      orow[dg * 16 + l16] = Oacc[dg][r] * inv;
  }
}

extern "C" void kernel_launch(void* const* d_in, const int* in_sizes, int n_in,
                              void* d_out, int out_size, void* d_ws, size_t ws_size,
                              hipStream_t stream) {
  const float* Q = (const float*)d_in[0];
  const float* K = (const float*)d_in[1];
  const float* V = (const float*)d_in[2];
  float* O = (float*)d_out;

  const size_t n_elem = (size_t)NBH * SLEN * DDIM;   // 16,777,216
  const size_t need   = n_elem * 2 * 2;              // Kb + Vt bf16

  if (ws_size >= need) {
    ushort_t* Kbf = (ushort_t*)d_ws;
    ushort_t* Vt  = Kbf + n_elem;
    prepass_kernel<<<2048 + 8192, 256, 0, stream>>>(K, V, Kbf, Vt);
    fattn5_kernel<<<dim3(SLEN / QB, NBH), dim3(512), 0, stream>>>(Q, Kbf, Vt, O);
  } else {
    fattn_kernel<<<dim3(SLEN / 64, NBH), dim3(256), 0, stream>>>(Q, K, V, O);
  }
}

// Round 6
// 146.022 us; speedup vs baseline: 1.0002x; 1.0002x over previous
//
#include <hip/hip_runtime.h>

// Flash-attention forward, causal, B=4 H=16 S=2048 D=128, fp32 in/out.
// Round 6: SAME structure as round 5 (3-buffer cross-tile pipeline), but
// __launch_bounds__(512, 1): removes the 128-VGPR cap that was forcing
// scratch spills of the 160+ live VGPRs (Oacc64+sacA32+sacB32+qf32).
// 1 WG/CU (96KB LDS), 8 waves, 2 waves/SIMD, ~256 VGPR - the AITER attn
// operating point.

#define SLEN 2048
#define DDIM 128
#define NBH  64
#define QB   256
#define KB   64

typedef __bf16 bf16x8 __attribute__((ext_vector_type(8)));
typedef float  f32x16 __attribute__((ext_vector_type(16)));
typedef float  f32x4  __attribute__((ext_vector_type(4)));
typedef unsigned uint32x4 __attribute__((ext_vector_type(4)));
typedef unsigned short ushort_t;
typedef ushort_t ushort8 __attribute__((ext_vector_type(8)));

__device__ inline ushort_t f2bf(float f) {
  union { float f; unsigned u; } v; v.f = f;
  unsigned u = v.u;
  u += 0x7FFFu + ((u >> 16) & 1u);   // RNE, finite inputs only
  return (ushort_t)(u >> 16);
}

__device__ inline unsigned cvtpk_bf16(float lo, float hi) {
  unsigned r;
  asm("v_cvt_pk_bf16_f32 %0, %1, %2" : "=v"(r) : "v"(lo), "v"(hi));
  return r;
}

__device__ inline float exp2_fast(float x) {
  float r;
  asm("v_exp_f32 %0, %1" : "=v"(r) : "v"(x));
  return r;
}

// ------------- fused pre-pass: K->bf16 convert + V->V^T bf16 -------------
__global__ __launch_bounds__(256) void prepass_kernel(
    const float* __restrict__ K, const float* __restrict__ V,
    ushort_t* __restrict__ Kb, ushort_t* __restrict__ Vt) {
  __shared__ float t[64][33];
  if (blockIdx.x < 2048) {            // ---- K convert ----
    const int n4 = (int)((size_t)NBH * SLEN * DDIM / 4);
    const int stride = 2048 * 256;
    for (int i = blockIdx.x * 256 + threadIdx.x; i < n4; i += stride) {
      float4 x = reinterpret_cast<const float4*>(K)[i];
      unsigned lo = (unsigned)f2bf(x.x) | ((unsigned)f2bf(x.y) << 16);
      unsigned hi = (unsigned)f2bf(x.z) | ((unsigned)f2bf(x.w) << 16);
      reinterpret_cast<uint2*>(Kb)[i] = make_uint2(lo, hi);
    }
  } else {                            // ---- V transpose ----
    const int vb = (int)blockIdx.x - 2048;     // 8192 blocks
    const int bh = vb >> 7;
    const int d0 = ((vb >> 5) & 3) * 32;
    const int s0 = (vb & 31) * 64;
    const int tx = threadIdx.x & 31;
    const int ty = threadIdx.x >> 5;
    const float* src = V + ((size_t)bh * SLEN + s0) * DDIM + d0;
#pragma unroll
    for (int j = 0; j < 8; ++j) {
      int sl = ty + j * 8;
      t[sl][tx] = src[(size_t)sl * DDIM + tx];
    }
    __syncthreads();
    ushort_t* dst = Vt + ((size_t)bh * DDIM + d0) * SLEN + s0;
#pragma unroll
    for (int j = 0; j < 4; ++j) {
      int dl = ty + j * 8;
      unsigned lo = f2bf(t[tx * 2][dl]);
      unsigned hi = f2bf(t[tx * 2 + 1][dl]);
      *reinterpret_cast<unsigned*>(&dst[(size_t)dl * SLEN + tx * 2]) =
          lo | (hi << 16);
    }
  }
}

// ---- QK^T for tile TT into S[2] (no setprio: let softmax interleave) ----
#define QKT(S, TT) do {                                                      \
    const int _b = (TT) % 3;                                                 \
    _Pragma("unroll")                                                        \
    for (int mt = 0; mt < 2; ++mt) {                                         \
      f32x16 a;                                                              \
      _Pragma("unroll")                                                      \
      for (int r = 0; r < 16; ++r) a[r] = 0.f;                               \
      int row = mt * 32 + l31;                                               \
      int sw = row & 7;                                                      \
      _Pragma("unroll")                                                      \
      for (int ds = 0; ds < 8; ++ds) {                                       \
        int c = ds * 2 + hi;                                                 \
        bf16x8 kf = *reinterpret_cast<const bf16x8*>(                        \
            &K_sh[_b][row * DDIM + ((c ^ sw) << 3)]);                        \
        a = __builtin_amdgcn_mfma_f32_32x32x16_bf16(kf, qf[ds], a, 0, 0, 0); \
      }                                                                      \
      S[mt] = a;                                                             \
    }                                                                        \
  } while (0)

// ---- mask + online softmax + cvt/permlane + PV for tile U on S[2] ----
#define FINISH(S, U) do {                                                    \
    const int _u = (U);                                                      \
    const int _vb = _u % 3;                                                  \
    if (_u * 64 + 63 > q0w) {                                                \
      _Pragma("unroll")                                                      \
      for (int mt = 0; mt < 2; ++mt) {                                       \
        int kbase = _u * 64 + mt * 32 + 4 * hi;                              \
        _Pragma("unroll")                                                    \
        for (int r = 0; r < 16; ++r) {                                       \
          int krow = (r & 3) + 8 * (r >> 2);                                 \
          if (kbase + krow > qg) S[mt][r] = -3.0e38f;                        \
        }                                                                    \
      }                                                                      \
    }                                                                        \
    float p0 = S[0][0], p1 = S[0][1], p2 = S[0][2], p3 = S[0][3];            \
    _Pragma("unroll")                                                        \
    for (int r = 4; r < 16; r += 4) {                                        \
      p0 = fmaxf(p0, S[0][r]);     p1 = fmaxf(p1, S[0][r + 1]);              \
      p2 = fmaxf(p2, S[0][r + 2]); p3 = fmaxf(p3, S[0][r + 3]);              \
    }                                                                        \
    _Pragma("unroll")                                                        \
    for (int r = 0; r < 16; r += 4) {                                        \
      p0 = fmaxf(p0, S[1][r]);     p1 = fmaxf(p1, S[1][r + 1]);              \
      p2 = fmaxf(p2, S[1][r + 2]); p3 = fmaxf(p3, S[1][r + 3]);              \
    }                                                                        \
    float tm = fmaxf(fmaxf(p0, p1), fmaxf(p2, p3));                          \
    tm = fmaxf(tm, __shfl_xor(tm, 32));                                      \
    if (!__all(tm - m_run <= THR)) {                                         \
      float mnew  = fmaxf(m_run, tm);                                        \
      float alpha = exp2_fast(m_run - mnew);                                 \
      m_run = mnew; l_run *= alpha;                                          \
      _Pragma("unroll")                                                      \
      for (int dt = 0; dt < 4; ++dt)                                         \
        _Pragma("unroll")                                                    \
        for (int r = 0; r < 16; ++r) Oacc[dt][r] *= alpha;                   \
    }                                                                        \
    float s0 = 0.f, s1 = 0.f, s2 = 0.f, s3 = 0.f;                            \
    _Pragma("unroll")                                                        \
    for (int mt = 0; mt < 2; ++mt)                                           \
      _Pragma("unroll")                                                      \
      for (int r = 0; r < 16; r += 4) {                                      \
        float e0 = exp2_fast(S[mt][r + 0] - m_run);                          \
        float e1 = exp2_fast(S[mt][r + 1] - m_run);                          \
        float e2 = exp2_fast(S[mt][r + 2] - m_run);                          \
        float e3 = exp2_fast(S[mt][r + 3] - m_run);                          \
        S[mt][r + 0] = e0; S[mt][r + 1] = e1;                                \
        S[mt][r + 2] = e2; S[mt][r + 3] = e3;                                \
        s0 += e0; s1 += e1; s2 += e2; s3 += e3;                              \
      }                                                                      \
    float rs = (s0 + s1) + (s2 + s3);                                        \
    rs += __shfl_xor(rs, 32);                                                \
    l_run += rs;                                                             \
    uint32x4 pw[4];                                                          \
    _Pragma("unroll")                                                        \
    for (int ks = 0; ks < 4; ++ks) {                                         \
      const int mt = ks >> 1;                                                \
      const int hb = 8 * (ks & 1);                                           \
      unsigned X  = cvtpk_bf16(S[mt][hb + 0], S[mt][hb + 1]);                \
      unsigned X2 = cvtpk_bf16(S[mt][hb + 2], S[mt][hb + 3]);                \
      unsigned Y  = cvtpk_bf16(S[mt][hb + 4], S[mt][hb + 5]);                \
      unsigned Y2 = cvtpk_bf16(S[mt][hb + 6], S[mt][hb + 7]);                \
      asm("v_permlane32_swap_b32 %0, %1" : "+v"(X),  "+v"(Y));               \
      asm("v_permlane32_swap_b32 %0, %1" : "+v"(X2), "+v"(Y2));              \
      uint32x4 f; f.x = X; f.y = X2; f.z = Y; f.w = Y2;                      \
      pw[ks] = f;                                                            \
    }                                                                        \
    _Pragma("unroll")                                                        \
    for (int dt = 0; dt < 4; ++dt) {                                         \
      int row = dt * 32 + l31;                                               \
      int sw = row & 7;                                                      \
      __builtin_amdgcn_s_setprio(1);                                         \
      _Pragma("unroll")                                                      \
      for (int ks = 0; ks < 4; ++ks) {                                       \
        int c = ks * 2 + hi;                                                 \
        bf16x8 vf = *reinterpret_cast<const bf16x8*>(                        \
            &V_sh[_vb][row * 64 + ((c ^ sw) << 3)]);                         \
        Oacc[dt] = __builtin_amdgcn_mfma_f32_32x32x16_bf16(                  \
            vf, __builtin_bit_cast(bf16x8, pw[ks]), Oacc[dt], 0, 0, 0);      \
      }                                                                      \
      __builtin_amdgcn_s_setprio(0);                                         \
    }                                                                        \
  } while (0)

// ---------------- main kernel: 8 waves, 32x32 MFMA, pipelined ----------------
__global__ __launch_bounds__(512, 1) void fattn6_kernel(
    const float* __restrict__ Q, const ushort_t* __restrict__ Kb,
    const ushort_t* __restrict__ Vt, float* __restrict__ Out) {
  __shared__ ushort_t K_sh[3][KB * DDIM];   // 3 x 16KB
  __shared__ ushort_t V_sh[3][DDIM * KB];   // 3 x 16KB

  const int tid  = threadIdx.x;
  const int lane = tid & 63;
  const int wv   = tid >> 6;         // 0..7
  const int l31  = lane & 31;
  const int hi   = lane >> 5;        // 0/1
  const int qblk = (blockIdx.y >= 32) ? blockIdx.x : (7 - (int)blockIdx.x);
  const int bh   = blockIdx.y;

  // 1/sqrt(128) * log2(e): softmax runs in exp2 domain
  const float qscale = 0.12751744f;
  const float THR = 11.0f;           // defer-max threshold (log2 units)

  const float*    Qp = Q  + (size_t)bh * SLEN * DDIM;
  const ushort_t* Kp = Kb + (size_t)bh * SLEN * DDIM;
  const ushort_t* Vp = Vt + (size_t)bh * DDIM * SLEN;
  float*          Op = Out + (size_t)bh * SLEN * DDIM;

  const int q0w = qblk * QB + wv * 32;   // wave's first q row
  const int qg  = q0w + l31;             // this lane's q row

  // ---- Q fragments: B-operand of S^T = K·Q^T ----
  bf16x8 qf[8];
  {
    const float* qr = Qp + (size_t)qg * DDIM;
#pragma unroll
    for (int ds = 0; ds < 8; ++ds) {
      int d0 = ds * 16 + hi * 8;
      float4 x = *reinterpret_cast<const float4*>(qr + d0);
      float4 y = *reinterpret_cast<const float4*>(qr + d0 + 4);
      ushort8 uu;
      uu[0] = f2bf(x.x * qscale); uu[1] = f2bf(x.y * qscale);
      uu[2] = f2bf(x.z * qscale); uu[3] = f2bf(x.w * qscale);
      uu[4] = f2bf(y.x * qscale); uu[5] = f2bf(y.y * qscale);
      uu[6] = f2bf(y.z * qscale); uu[7] = f2bf(y.w * qscale);
      qf[ds] = __builtin_bit_cast(bf16x8, uu);
    }
  }

  f32x16 Oacc[4];
#pragma unroll
  for (int dt = 0; dt < 4; ++dt)
#pragma unroll
    for (int r = 0; r < 16; ++r) Oacc[dt][r] = 0.f;
  float m_run = -3.0e38f, l_run = 0.f;

  const int last_kb = qblk * 4 + 3;          // WG-uniform; ntiles = 4qblk+4
  const int lkw     = 4 * qblk + (wv >> 1);  // wave's last needed tile

  auto stage = [&](int buf, int kb) {
    const ushort_t* ksrc = Kp + (size_t)kb * KB * DDIM;
#pragma unroll
    for (int j = 0; j < 2; ++j) {
      int chunk = wv * 128 + j * 64 + lane;
      int row = chunk >> 4, c = chunk & 15;
      const ushort_t* g = ksrc + row * DDIM + ((c ^ (row & 7)) << 3);
      ushort_t* l = &K_sh[buf][(wv * 128 + j * 64) * 8];
      __builtin_amdgcn_global_load_lds(
          (const __attribute__((address_space(1))) unsigned*)g,
          (__attribute__((address_space(3))) unsigned*)l, 16, 0, 0);
    }
    const ushort_t* vsrc = Vp + (size_t)kb * KB;
#pragma unroll
    for (int j = 0; j < 2; ++j) {
      int chunk = wv * 128 + j * 64 + lane;
      int row = chunk >> 3, c = chunk & 7;
      const ushort_t* g = vsrc + (size_t)row * SLEN + ((c ^ (row & 7)) << 3);
      ushort_t* l = &V_sh[buf][(wv * 128 + j * 64) * 8];
      __builtin_amdgcn_global_load_lds(
          (const __attribute__((address_space(1))) unsigned*)g,
          (__attribute__((address_space(3))) unsigned*)l, 16, 0, 0);
    }
  };

  f32x16 sacA[2], sacB[2];

  stage(0, 0);

  // ---- peel t = 0 ----
  __syncthreads();
  stage(1, 1);
  QKT(sacA, 0);

  // ---- peel t = 1 ----
  __syncthreads();
  if (1 < last_kb) stage(2, 2);
  if (1 <= lkw)           { QKT(sacB, 1); FINISH(sacA, 0); }
  else if (lkw == 0)      { FINISH(sacA, 0); }

  // ---- main pipeline, 2 tiles per iteration ----
  for (int t = 2; t <= last_kb; t += 2) {
    __syncthreads();
    if (t < last_kb) stage((t + 1) % 3, t + 1);
    if (t <= lkw)            { QKT(sacA, t); FINISH(sacB, t - 1); }
    else if (t == lkw + 1)   { FINISH(sacB, t - 1); }

    __syncthreads();
    if (t + 1 < last_kb) stage((t + 2) % 3, t + 2);
    if (t + 1 <= lkw)          { QKT(sacB, t + 1); FINISH(sacA, t); }
    else if (t + 1 == lkw + 1) { FINISH(sacA, t); }
  }

  // ---- drain: tile last_kb (odd -> sacB) for waves that needed it ----
  if (lkw == last_kb) { FINISH(sacB, last_kb); }

  // ---- epilogue: O[q][d] = O^T normalized, float4 stores ----
  {
    float invl = 1.0f / l_run;
    float* orow = Op + (size_t)qg * DDIM;
#pragma unroll
    for (int dt = 0; dt < 4; ++dt)
#pragma unroll
      for (int rq = 0; rq < 4; ++rq) {
        float4 o;
        o.x = Oacc[dt][rq * 4 + 0] * invl;
        o.y = Oacc[dt][rq * 4 + 1] * invl;
        o.z = Oacc[dt][rq * 4 + 2] * invl;
        o.w = Oacc[dt][rq * 4 + 3] * invl;
        int d = dt * 32 + 8 * rq + 4 * hi;
        *reinterpret_cast<float4*>(orow + d) = o;
      }
  }
}

// ---------------- fallback (fp32-direct kernel, used if ws too small) --------
__global__ __launch_bounds__(256) void fattn_kernel(
    const float* __restrict__ Q, const float* __restrict__ K,
    const float* __restrict__ V, float* __restrict__ Out) {
  __shared__ ushort_t Kf_sh[64 * 128];
  __shared__ ushort_t Vf_sh[128 * 64];
  __shared__ ushort_t P_sh[4][16 * 64];

  const int tid  = threadIdx.x;
  const int lane = tid & 63;
  const int wv   = tid >> 6;
  const int l16  = lane & 15;
  const int lhi  = lane >> 4;
  const int qblk = blockIdx.x;
  const int bh   = blockIdx.y;
  const float scale = 0.08838834764831845f;

  const size_t base = (size_t)bh * SLEN * DDIM;
  const float* Qp = Q + base;
  const float* Kp = K + base;
  const float* Vp = V + base;
  float*       Op = Out + base;

  bf16x8 qf[4];
  {
    const int qrow = qblk * 64 + wv * 16 + l16;
    const float* qr = Qp + (size_t)qrow * DDIM;
#pragma unroll
    for (int dc = 0; dc < 4; ++dc) {
      int d0 = dc * 32 + lhi * 8;
      float4 x = *reinterpret_cast<const float4*>(qr + d0);
      float4 y = *reinterpret_cast<const float4*>(qr + d0 + 4);
      ushort8 uu;
      uu[0] = f2bf(x.x * scale); uu[1] = f2bf(x.y * scale);
      uu[2] = f2bf(x.z * scale); uu[3] = f2bf(x.w * scale);
      uu[4] = f2bf(y.x * scale); uu[5] = f2bf(y.y * scale);
      uu[6] = f2bf(y.z * scale); uu[7] = f2bf(y.w * scale);
      qf[dc] = __builtin_bit_cast(bf16x8, uu);
    }
  }

  f32x4 Oacc[8];
#pragma unroll
  for (int i = 0; i < 8; ++i) Oacc[i] = (f32x4){0.f, 0.f, 0.f, 0.f};
  float m_run[4], l_run[4];
#pragma unroll
  for (int r = 0; r < 4; ++r) { m_run[r] = -3.0e38f; l_run[r] = 0.f; }

  for (int kb = 0; kb <= qblk; ++kb) {
    __syncthreads();
    {
      const float* src = Kp + (size_t)kb * 64 * DDIM;
#pragma unroll
      for (int it = 0; it < 8; ++it) {
        int idx4 = it * 256 + tid;
        int r  = idx4 >> 5;
        int c4 = idx4 & 31;
        float4 x = *reinterpret_cast<const float4*>(src + r * DDIM + c4 * 4);
        unsigned lo = ((unsigned)f2bf(x.y) << 16) | f2bf(x.x);
        unsigned hh = ((unsigned)f2bf(x.w) << 16) | f2bf(x.z);
        int e = (r * 128 + c4 * 4) ^ ((r & 7) << 3);
        *reinterpret_cast<uint2*>(&Kf_sh[e]) = make_uint2(lo, hh);
      }
      const float* vs = Vp + (size_t)kb * 64 * DDIM;
#pragma unroll
      for (int it = 0; it < 8; ++it) {
        int idx4 = it * 256 + tid;
        int r  = idx4 >> 5;
        int c4 = idx4 & 31;
        float4 x = *reinterpret_cast<const float4*>(vs + r * DDIM + c4 * 4);
        int c0 = c4 * 4;
        float vals[4] = {x.x, x.y, x.z, x.w};
#pragma unroll
        for (int j = 0; j < 4; ++j) {
          int d = c0 + j;
          Vf_sh[(d * 64 + r) ^ ((d & 7) << 3)] = f2bf(vals[j]);
        }
      }
    }
    __syncthreads();

    f32x4 sacc[4];
#pragma unroll
    for (int g = 0; g < 4; ++g) {
      f32x4 acc = (f32x4){0.f, 0.f, 0.f, 0.f};
#pragma unroll
      for (int dc = 0; dc < 4; ++dc) {
        int row = g * 16 + l16;
        int e = (row * 128 + dc * 32 + lhi * 8) ^ ((row & 7) << 3);
        bf16x8 kf = *reinterpret_cast<const bf16x8*>(&Kf_sh[e]);
        acc = __builtin_amdgcn_mfma_f32_16x16x32_bf16(qf[dc], kf, acc, 0, 0, 0);
      }
      sacc[g] = acc;
    }

    if (kb == qblk) {
      int q0 = lhi * 4;
#pragma unroll
      for (int g = 0; g < 4; ++g) {
        int kcol = g * 16 + l16;
#pragma unroll
        for (int r = 0; r < 4; ++r) {
          if (kcol > wv * 16 + q0 + r) sacc[g][r] = -3.0e38f;
        }
      }
    }

    float tmax[4];
#pragma unroll
    for (int r = 0; r < 4; ++r)
      tmax[r] = fmaxf(fmaxf(sacc[0][r], sacc[1][r]),
                      fmaxf(sacc[2][r], sacc[3][r]));
#pragma unroll
    for (int x = 1; x < 16; x <<= 1) {
#pragma unroll
      for (int r = 0; r < 4; ++r)
        tmax[r] = fmaxf(tmax[r], __shfl_xor(tmax[r], x));
    }

    float alpha[4], mnew[4];
#pragma unroll
    for (int r = 0; r < 4; ++r) {
      mnew[r]  = fmaxf(m_run[r], tmax[r]);
      alpha[r] = __expf(m_run[r] - mnew[r]);
      m_run[r] = mnew[r];
    }

    float rsum[4] = {0.f, 0.f, 0.f, 0.f};
#pragma unroll
    for (int g = 0; g < 4; ++g) {
#pragma unroll
      for (int r = 0; r < 4; ++r) {
        float p = __expf(sacc[g][r] - mnew[r]);
        rsum[r] += p;
        int prow = lhi * 4 + r;
        P_sh[wv][(prow * 64 + g * 16 + l16) ^ ((prow & 7) << 3)] = f2bf(p);
      }
    }
#pragma unroll
    for (int x = 1; x < 16; x <<= 1) {
#pragma unroll
      for (int r = 0; r < 4; ++r) rsum[r] += __shfl_xor(rsum[r], x);
    }
#pragma unroll
    for (int r = 0; r < 4; ++r) l_run[r] = l_run[r] * alpha[r] + rsum[r];

#pragma unroll
    for (int dg = 0; dg < 8; ++dg)
#pragma unroll
      for (int r = 0; r < 4; ++r) Oacc[dg][r] *= alpha[r];

    bf16x8 pf[2];
#pragma unroll
    for (int kc = 0; kc < 2; ++kc) {
      int e = (l16 * 64 + kc * 32 + lhi * 8) ^ ((l16 & 7) << 3);
      pf[kc] = *reinterpret_cast<const bf16x8*>(&P_sh[wv][e]);
    }
#pragma unroll
    for (int dg = 0; dg < 8; ++dg) {
#pragma unroll
      for (int kc = 0; kc < 2; ++kc) {
        int row = dg * 16 + l16;
        int e = (row * 64 + kc * 32 + lhi * 8) ^ ((row & 7) << 3);
        bf16x8 vf = *reinterpret_cast<const bf16x8*>(&Vf_sh[e]);
        Oacc[dg] = __builtin_amdgcn_mfma_f32_16x16x32_bf16(pf[kc], vf, Oacc[dg], 0, 0, 0);
      }
    }
  }

#pragma unroll
  for (int r = 0; r < 4; ++r) {
    float inv = 1.0f / l_run[r];
    int q = qblk * 64 + wv * 16 + lhi * 4 + r;
    float* orow = Op + (size_t)q * DDIM;
#pragma unroll
    for (int dg = 0; dg < 8; ++dg)
      orow[dg * 16 + l16] = Oacc[dg][r] * inv;
  }
}

extern "C" void kernel_launch(void* const* d_in, const int* in_sizes, int n_in,
                              void* d_out, int out_size, void* d_ws, size_t ws_size,
                              hipStream_t stream) {
  const float* Q = (const float*)d_in[0];
  const float* K = (const float*)d_in[1];
  const float* V = (const float*)d_in[2];
  float* O = (float*)d_out;

  const size_t n_elem = (size_t)NBH * SLEN * DDIM;   // 16,777,216
  const size_t need   = n_elem * 2 * 2;              // Kb + Vt bf16

  if (ws_size >= need) {
    ushort_t* Kbf = (ushort_t*)d_ws;
    ushort_t* Vt  = Kbf + n_elem;
    prepass_kernel<<<2048 + 8192, 256, 0, stream>>>(K, V, Kbf, Vt);
    fattn6_kernel<<<dim3(SLEN / QB, NBH), dim3(512), 0, stream>>>(Q, Kbf, Vt, O);
  } else {
    fattn_kernel<<<dim3(SLEN / 64, NBH), dim3(256), 0, stream>>>(Q, K, V, O);
  }
}